// Round 1
// baseline (17613.382 us; speedup 1.0000x reference)
//
#include <hip/hip_runtime.h>
#include <math.h>

#define BB 128
#define TT 512
#define U  512
#define G  2048   // 4*U

__device__ __forceinline__ float sigmoidf_(float x) {
    return 1.0f / (1.0f + __expf(-x));
}

__global__ void zero_ws(float* p, int n) {
    int i = blockIdx.x * blockDim.x + threadIdx.x;
    if (i < n) p[i] = 0.0f;
}

// One time step, both directions.
// grid: (32 unit-tiles, 8 batch-tiles, 2 dirs), block: 256
// hr: h read  buffer [2 dir][BB][U]  (state before this step)
// hw: h write buffer [2 dir][BB][U]  (state after this step)
// cbuf: c [2 dir][BB][U] (single-buffered: each element owned by exactly one WG)
__global__ __launch_bounds__(256, 2)
void lstm_step(const float* __restrict__ x,     // [BB][TT][3]
               const int*   __restrict__ mask,  // [BB][TT]
               const float* __restrict__ Wx_f, const float* __restrict__ Wh_f, const float* __restrict__ b_f,
               const float* __restrict__ Wx_b, const float* __restrict__ Wh_b, const float* __restrict__ b_b,
               const float* __restrict__ hr,
               float*       __restrict__ hw,
               float*       __restrict__ cbuf,
               float*       __restrict__ out,   // [BB][TT][1024]
               int t)
{
    const int ut  = blockIdx.x;          // unit tile: 16 units
    const int bt  = blockIdx.y;          // batch tile: 16 rows
    const int dir = blockIdx.z;
    const int tid = threadIdx.x;
    const int tau = dir ? (TT - 1 - t) : t;   // time index into x/mask/out

    const float* Wx   = dir ? Wx_b : Wx_f;
    const float* Wh   = dir ? Wh_b : Wh_f;
    const float* bias = dir ? b_b  : b_f;
    const float* hrd  = hr   + dir * BB * U;
    float*       hwd  = hw   + dir * BB * U;
    float*       cd   = cbuf + dir * BB * U;
    const int b0 = bt * 16;

    // stage transposed h tile: hT[k][r] = h[b0+r][k], padded to 17 to avoid bank conflicts
    __shared__ float hT[U][17];
    for (int idx = tid; idx < 16 * U; idx += 256) {
        int r = idx >> 9;          // 0..15
        int k = idx & (U - 1);     // 0..511  (consecutive tid -> consecutive k: coalesced)
        hT[k][r] = hrd[(b0 + r) * U + k];
    }

    // thread -> (row r, 4 columns of one gate)
    const int r    = tid & 15;
    const int cg   = tid >> 4;           // 0..15
    const int gate = cg >> 2;            // 0..3
    const int un   = (cg & 3) << 2;      // 0,4,8,12
    const int col  = gate * U + ut * 16 + un;   // 4 consecutive cols of z

    float4 acc = *reinterpret_cast<const float4*>(bias + col);

    // x_t @ Wx contribution (D=3)
    const float* xr = x + ((size_t)(b0 + r) * TT + tau) * 3;
    float x0 = xr[0], x1 = xr[1], x2 = xr[2];
    float4 w0 = *reinterpret_cast<const float4*>(Wx + 0 * G + col);
    float4 w1 = *reinterpret_cast<const float4*>(Wx + 1 * G + col);
    float4 w2 = *reinterpret_cast<const float4*>(Wx + 2 * G + col);
    acc.x += x0 * w0.x + x1 * w1.x + x2 * w2.x;
    acc.y += x0 * w0.y + x1 * w1.y + x2 * w2.y;
    acc.z += x0 * w0.z + x1 * w1.z + x2 * w2.z;
    acc.w += x0 * w0.w + x1 * w1.w + x2 * w2.w;

    __syncthreads();

    // h @ Wh: K=512 loop, 4 FMAs + 1 LDS scalar + 1 global float4 per k
    const float* wp = Wh + col;
    #pragma unroll 8
    for (int k = 0; k < U; ++k) {
        float hv = hT[k][r];
        float4 w = *reinterpret_cast<const float4*>(wp);
        acc.x = fmaf(hv, w.x, acc.x);
        acc.y = fmaf(hv, w.y, acc.y);
        acc.z = fmaf(hv, w.z, acc.z);
        acc.w = fmaf(hv, w.w, acc.w);
        wp += G;
    }

    // regroup gates via LDS so each thread gets all 4 gates of one (row, unit)
    __shared__ float zt[16][4][17];
    zt[r][gate][un + 0] = acc.x;
    zt[r][gate][un + 1] = acc.y;
    zt[r][gate][un + 2] = acc.z;
    zt[r][gate][un + 3] = acc.w;
    __syncthreads();

    {
        const int rr = tid & 15;
        const int uu = tid >> 4;              // 0..15
        const int gb = b0 + rr;
        const int gu = ut * 16 + uu;
        float zi = zt[rr][0][uu];
        float zf = zt[rr][1][uu];
        float zg = zt[rr][2][uu];
        float zo = zt[rr][3][uu];
        float cprev = cd[gb * U + gu];
        float hprev = hrd[gb * U + gu];
        float ig = sigmoidf_(zi);
        float fg = sigmoidf_(zf);
        float gg = tanhf(zg);
        float og = sigmoidf_(zo);
        float cn = fg * cprev + ig * gg;
        float hn = og * tanhf(cn);
        bool  m  = (mask[(size_t)gb * TT + tau] != 0);
        float h2 = m ? hn : hprev;
        float c2 = m ? cn : cprev;
        hwd[gb * U + gu] = h2;
        cd[gb * U + gu]  = c2;
        out[((size_t)gb * TT + tau) * 1024 + dir * 512 + gu] = h2;
    }
}

// finalize: write state_h, state_c, pos_agg
__global__ __launch_bounds__(256)
void finalize(const float* __restrict__ hfin,  // [2][BB][U]
              const float* __restrict__ cfin,  // [2][BB][U]
              const float* __restrict__ W1,    // [U][4]
              const float* __restrict__ b1,    // [4]
              float* __restrict__ out)
{
    const int b = blockIdx.x;
    const int tid = threadIdx.x;
    float* sh = out + (size_t)BB * TT * 1024;   // state_h [BB][2][U]
    float* sc = sh + (size_t)BB * 2 * U;        // state_c [BB][2][U]
    float* pa = sc + (size_t)BB * 2 * U;        // pos_agg [BB][8]
    for (int i = tid; i < 2 * U; i += 256) {
        int d = i / U, u = i % U;
        sh[(size_t)b * 2 * U + i] = hfin[(size_t)d * BB * U + b * U + u];
        sc[(size_t)b * 2 * U + i] = cfin[(size_t)d * BB * U + b * U + u];
    }
    if (tid < 8) {
        int d = tid >> 2, j = tid & 3;
        const float* hv = hfin + (size_t)d * BB * U + (size_t)b * U;
        float s = b1[j];
        for (int u = 0; u < U; ++u) s = fmaf(hv[u], W1[u * 4 + j], s);
        pa[b * 8 + tid] = s;
    }
}

extern "C" void kernel_launch(void* const* d_in, const int* in_sizes, int n_in,
                              void* d_out, int out_size, void* d_ws, size_t ws_size,
                              hipStream_t stream)
{
    (void)in_sizes; (void)n_in; (void)out_size; (void)ws_size;
    const float* x    = (const float*)d_in[0];
    const int*   mask = (const int*)d_in[1];
    const float* Wx_f = (const float*)d_in[2];
    const float* Wh_f = (const float*)d_in[3];
    const float* b_f  = (const float*)d_in[4];
    const float* Wx_b = (const float*)d_in[5];
    const float* Wh_b = (const float*)d_in[6];
    const float* b_b  = (const float*)d_in[7];
    const float* W1   = (const float*)d_in[8];
    const float* b1   = (const float*)d_in[9];
    float* out = (float*)d_out;

    // ws: h[2 phase][2 dir][BB][U], c[2 dir][BB][U]
    float* h = (float*)d_ws;
    float* c = h + 2 * 2 * BB * U;
    int ztotal = 2 * 2 * BB * U + 2 * BB * U;   // 393216 floats

    zero_ws<<<(ztotal + 255) / 256, 256, 0, stream>>>(h, ztotal);

    dim3 grid(32, 8, 2), block(256);
    for (int t = 0; t < TT; ++t) {
        const float* hrp = h + (size_t)(t & 1) * (2 * BB * U);
        float*       hwp = h + (size_t)((t + 1) & 1) * (2 * BB * U);
        lstm_step<<<grid, block, 0, stream>>>(x, mask, Wx_f, Wh_f, b_f,
                                              Wx_b, Wh_b, b_b,
                                              hrp, hwp, c, out, t);
    }
    // after t=511, final h is in phase (512 & 1) == 0 -> h base
    finalize<<<BB, 256, 0, stream>>>(h, c, W1, b1, out);
}

// Round 4
// 5466.383 us; speedup vs baseline: 3.2221x; 3.2221x over previous
//
#include <hip/hip_runtime.h>
#include <hip/hip_bf16.h>
#include <math.h>

#define BB 128
#define TT 512
#define U  512
#define G  2048   // 4*U

typedef short short8 __attribute__((ext_vector_type(8)));
typedef float floatx4 __attribute__((ext_vector_type(4)));

__device__ __forceinline__ float sigmoidf_(float x) {
    return 1.0f / (1.0f + __expf(-x));
}

// ---------------- prep: Wh [512][2048] -> WhPT [d][c][k] bf16, c = u*4+g ----
// grid (16 k-tiles, 64 col-tiles, 2), block 256
__global__ __launch_bounds__(256)
void prep_wh(const float* __restrict__ Wh_f, const float* __restrict__ Wh_b,
             __hip_bfloat16* __restrict__ WhPT)
{
    const int kt = blockIdx.x, ct = blockIdx.y, d = blockIdx.z;
    const float* Wh = d ? Wh_b : Wh_f;
    const int tx = threadIdx.x & 31, ty = threadIdx.x >> 5;  // tx:0..31, ty:0..7
    __shared__ float tile[32][33];
    #pragma unroll
    for (int i = 0; i < 4; ++i) {
        int r = ty + 8 * i;                       // k-local
        tile[r][tx] = Wh[(size_t)(kt * 32 + r) * G + ct * 32 + tx];
    }
    __syncthreads();
    #pragma unroll
    for (int i = 0; i < 4; ++i) {
        int colLocal = ty + 8 * i;
        int col = ct * 32 + colLocal;             // original col: g*512+u
        int c = ((col & 511) << 2) | (col >> 9);  // u*4+g
        WhPT[((size_t)d * G + c) * U + kt * 32 + tx] =
            __float2bfloat16(tile[tx][colLocal]);
    }
}

// ---------------- prep: WxbP [d][4][c] fp32 (rows 0..2 = Wx, row 3 = bias) --
__global__ __launch_bounds__(256)
void prep_wxb(const float* __restrict__ Wx_f, const float* __restrict__ b_f,
              const float* __restrict__ Wx_b, const float* __restrict__ b_b,
              float* __restrict__ WxbP)
{
    int idx = blockIdx.x * blockDim.x + threadIdx.x;   // 0 .. 2*2048-1
    if (idx >= 2 * G) return;
    int d = idx / G, c = idx % G;
    const float* Wx = d ? Wx_b : Wx_f;
    const float* bb = d ? b_b  : b_f;
    int col = ((c & 3) << 9) | (c >> 2);               // g*512+u
    WxbP[((size_t)d * 4 + 0) * G + c] = Wx[0 * G + col];
    WxbP[((size_t)d * 4 + 1) * G + c] = Wx[1 * G + col];
    WxbP[((size_t)d * 4 + 2) * G + c] = Wx[2 * G + col];
    WxbP[((size_t)d * 4 + 3) * G + c] = bb[col];
}

// ---------------- init: zero h (both phases, bf16) and c (fp32) ------------
__global__ void init_state(__hip_bfloat16* h, float* c, int nh, int nc)
{
    int i = blockIdx.x * blockDim.x + threadIdx.x;
    if (i < nh) h[i] = __float2bfloat16(0.0f);
    if (i < nc) c[i] = 0.0f;
}

// ---------------- one step: GEMM (MFMA) + fused gate epilogue --------------
// grid (64 col-tiles of 32, 8 row-tiles of 16, 2 dirs), block 64 (1 wave)
__global__ __launch_bounds__(64)
void lstm_step(const float* __restrict__ x,       // [BB][TT][3]
               const int*   __restrict__ mask,    // [BB][TT]
               const __hip_bfloat16* __restrict__ WhPT,  // [2][G][U]
               const float* __restrict__ WxbP,    // [2][4][G]
               const __hip_bfloat16* __restrict__ hr,    // [2][BB][U] read
               __hip_bfloat16*       __restrict__ hw,    // [2][BB][U] write
               float*       __restrict__ cws,     // [2][BB][U]
               float*       __restrict__ out,     // [BB][TT][1024]
               int t)
{
    const int ct = blockIdx.x;            // 32 cols
    const int rt = blockIdx.y;            // 16 rows
    const int d  = blockIdx.z;
    const int l  = threadIdx.x;           // 0..63
    const int tau = d ? (TT - 1 - t) : t;

    const short* A  = (const short*)(hr + (size_t)d * BB * U);
    const short* Bp = (const short*)(WhPT + (size_t)d * G * U);
    const int r0 = rt * 16;
    const int c0 = ct * 32;

    const int arow = r0 + (l & 15);
    const int kofs = (l >> 4) * 8;
    const int bc0  = c0 + (l & 15);

    floatx4 acc0 = {0.f, 0.f, 0.f, 0.f};
    floatx4 acc1 = {0.f, 0.f, 0.f, 0.f};

    #pragma unroll
    for (int kk = 0; kk < 16; ++kk) {
        int k = kk * 32 + kofs;
        short8 a  = *(const short8*)(A  + (size_t)arow * U + k);
        short8 b0 = *(const short8*)(Bp + (size_t)bc0        * U + k);
        short8 b1 = *(const short8*)(Bp + (size_t)(bc0 + 16) * U + k);
        acc0 = __builtin_amdgcn_mfma_f32_16x16x32_bf16(a, b0, acc0, 0, 0, 0);
        acc1 = __builtin_amdgcn_mfma_f32_16x16x32_bf16(a, b1, acc1, 0, 0, 0);
    }

    // C layout: col = lane&15, row = (lane>>4)*4 + reg
    __shared__ float z[16][36];
    {
        int rl = (l >> 4) * 4;
        int cl = l & 15;
        #pragma unroll
        for (int j = 0; j < 4; ++j) {
            z[rl + j][cl]      = acc0[j];
            z[rl + j][cl + 16] = acc1[j];
        }
    }
    __syncthreads();

    // epilogue: 128 (row, unit) pairs, 2 per lane
    const float* WxbD = WxbP + (size_t)d * 4 * G;
    #pragma unroll
    for (int p = 0; p < 2; ++p) {
        int row = l & 15;
        int un  = (l >> 4) + 4 * p;          // 0..7 local unit
        int b   = r0 + row;
        int u   = ct * 8 + un;               // global unit: c0/4 + un
        int c4  = c0 + un * 4;               // permuted col of gate 0

        floatx4 zz  = *(const floatx4*)&z[row][un * 4];
        floatx4 wx0 = *(const floatx4*)(WxbD + 0 * G + c4);
        floatx4 wx1 = *(const floatx4*)(WxbD + 1 * G + c4);
        floatx4 wx2 = *(const floatx4*)(WxbD + 2 * G + c4);
        floatx4 wb  = *(const floatx4*)(WxbD + 3 * G + c4);

        const float* xr = x + ((size_t)b * TT + tau) * 3;
        float x0 = xr[0], x1 = xr[1], x2 = xr[2];

        float zi = zz[0] + x0 * wx0[0] + x1 * wx1[0] + x2 * wx2[0] + wb[0];
        float zf = zz[1] + x0 * wx0[1] + x1 * wx1[1] + x2 * wx2[1] + wb[1];
        float zg = zz[2] + x0 * wx0[2] + x1 * wx1[2] + x2 * wx2[2] + wb[2];
        float zo = zz[3] + x0 * wx0[3] + x1 * wx1[3] + x2 * wx2[3] + wb[3];

        float ig = sigmoidf_(zi);
        float fg = sigmoidf_(zf);
        float gg = tanhf(zg);
        float og = sigmoidf_(zo);

        size_t su = (size_t)d * BB * U + (size_t)b * U + u;
        float cprev = cws[su];
        float hprev = __bfloat162float(hr[su]);
        float cn = fg * cprev + ig * gg;
        float hn = og * tanhf(cn);
        bool  m  = (mask[(size_t)b * TT + tau] != 0);
        float h2 = m ? hn : hprev;
        float c2 = m ? cn : cprev;
        cws[su] = c2;
        hw[su]  = __float2bfloat16(h2);
        out[((size_t)b * TT + tau) * 1024 + d * 512 + u] = h2;
    }
}

// ---------------- finalize: states + pos_agg -------------------------------
__global__ __launch_bounds__(256)
void finalize(const __hip_bfloat16* __restrict__ hfin,  // [2][BB][U]
              const float* __restrict__ cfin,           // [2][BB][U]
              const float* __restrict__ W1,             // [U][4]
              const float* __restrict__ b1,             // [4]
              float* __restrict__ out)
{
    const int b = blockIdx.x;
    const int tid = threadIdx.x;
    float* sh = out + (size_t)BB * TT * 1024;   // state_h [BB][2][U]
    float* sc = sh + (size_t)BB * 2 * U;        // state_c [BB][2][U]
    float* pa = sc + (size_t)BB * 2 * U;        // pos_agg [BB][8]
    for (int i = tid; i < 2 * U; i += 256) {
        int d = i / U, u = i % U;
        sh[(size_t)b * 2 * U + i] = __bfloat162float(hfin[(size_t)d * BB * U + b * U + u]);
        sc[(size_t)b * 2 * U + i] = cfin[(size_t)d * BB * U + b * U + u];
    }
    __shared__ float red[8][8];
    if (tid < 64) {
        int j = tid & 7;          // output index 0..7
        int seg = tid >> 3;       // 0..7
        int dd = j >> 2, jj = j & 3;
        const __hip_bfloat16* hv = hfin + (size_t)dd * BB * U + (size_t)b * U;
        float s = 0.f;
        for (int u = seg * 64; u < seg * 64 + 64; ++u)
            s = fmaf(__bfloat162float(hv[u]), W1[u * 4 + jj], s);
        red[seg][j] = s;
    }
    __syncthreads();
    if (tid < 8) {
        float s = b1[tid & 3];
        #pragma unroll
        for (int seg = 0; seg < 8; ++seg) s += red[seg][tid];
        pa[b * 8 + tid] = s;
    }
}

extern "C" void kernel_launch(void* const* d_in, const int* in_sizes, int n_in,
                              void* d_out, int out_size, void* d_ws, size_t ws_size,
                              hipStream_t stream)
{
    (void)in_sizes; (void)n_in; (void)out_size; (void)ws_size;
    const float* x    = (const float*)d_in[0];
    const int*   mask = (const int*)d_in[1];
    const float* Wx_f = (const float*)d_in[2];
    const float* Wh_f = (const float*)d_in[3];
    const float* b_f  = (const float*)d_in[4];
    const float* Wx_b = (const float*)d_in[5];
    const float* Wh_b = (const float*)d_in[6];
    const float* b_b  = (const float*)d_in[7];
    const float* W1   = (const float*)d_in[8];
    const float* b1   = (const float*)d_in[9];
    float* out = (float*)d_out;

    // ws layout:
    //   WhPT  bf16 [2][G][U]          = 2*2048*512*2B  = 4 MiB
    //   WxbP  f32  [2][4][G]          = 64 KiB
    //   h     bf16 [2 phase][2][BB][U]= 1 MiB
    //   c     f32  [2][BB][U]         = 512 KiB
    char* wsb = (char*)d_ws;
    __hip_bfloat16* WhPT = (__hip_bfloat16*)wsb;                 wsb += (size_t)2 * G * U * 2;
    float*          WxbP = (float*)wsb;                          wsb += (size_t)2 * 4 * G * 4;
    __hip_bfloat16* hbuf = (__hip_bfloat16*)wsb;                 wsb += (size_t)2 * 2 * BB * U * 2;
    float*          cbuf = (float*)wsb;

    const int PH = 2 * BB * U;   // elements per h phase

    prep_wh<<<dim3(16, 64, 2), 256, 0, stream>>>(Wh_f, Wh_b, WhPT);
    prep_wxb<<<(2 * G + 255) / 256, 256, 0, stream>>>(Wx_f, b_f, Wx_b, b_b, WxbP);
    init_state<<<(2 * PH + 255) / 256, 256, 0, stream>>>(hbuf, cbuf, 2 * PH, PH);

    dim3 grid(64, 8, 2), block(64);
    for (int t = 0; t < TT; ++t) {
        const __hip_bfloat16* hrp = hbuf + (size_t)(t & 1) * PH;
        __hip_bfloat16*       hwp = hbuf + (size_t)((t + 1) & 1) * PH;
        lstm_step<<<grid, block, 0, stream>>>(x, mask, WhPT, WxbP,
                                              hrp, hwp, cbuf, out, t);
    }
    finalize<<<BB, 256, 0, stream>>>(hbuf, cbuf, W1, b1, out);  // phase 0 after 512 steps
}